// Round 11
// baseline (355.707 us; speedup 1.0000x reference)
//
#include <hip/hip_runtime.h>
#include <hip/hip_bf16.h>
#include <math.h>

#define B_ 32
#define S_ 2048
#define D_ 1024
#define TEMP_ 9.0f

typedef __attribute__((ext_vector_type(8))) short short8;
typedef __attribute__((ext_vector_type(4))) float f32x4;
typedef __attribute__((ext_vector_type(4))) unsigned short ushort4v;

__device__ __forceinline__ unsigned short f2b(float f) {
  union { float f; unsigned int u; } v; v.f = f;
  unsigned int r = v.u;
  r += 0x7fffu + ((r >> 16) & 1u);   // RNE
  return (unsigned short)(r >> 16);
}
__device__ __forceinline__ float b2f(unsigned short b) {
  union { float f; unsigned int u; } v; v.u = ((unsigned int)b) << 16;
  return v.f;
}
// fast tanh: 1 - 2/(e^2x + 1); saturates correctly at +-inf
__device__ __forceinline__ float tanh_fast(float x) {
  float ez = __expf(2.f * x);
  return 1.f - __fdividef(2.f, ez + 1.f);
}

#define GLOAD_LDS16(g, l) \
  __builtin_amdgcn_global_load_lds((const __attribute__((address_space(1))) void*)(g), \
                                   (__attribute__((address_space(3))) void*)(l), 16, 0, 0)

// ---------------- K_conv: f32 -> bf16, 8 elements/thread ----------------
__global__ void k_conv(const float* __restrict__ src, unsigned short* __restrict__ dst, int n8) {
  int i = blockIdx.x * 256 + threadIdx.x;
  if (i >= n8) return;
  const float4* g = reinterpret_cast<const float4*>(src) + (size_t)i * 2;
  float4 x0 = g[0], x1 = g[1];
  uint4 w;
  w.x = f2b(x0.x) | ((unsigned)f2b(x0.y) << 16);
  w.y = f2b(x0.z) | ((unsigned)f2b(x0.w) << 16);
  w.z = f2b(x1.x) | ((unsigned)f2b(x1.y) << 16);
  w.w = f2b(x1.z) | ((unsigned)f2b(x1.w) << 16);
  reinterpret_cast<uint4*>(dst)[i] = w;
}

// ---------------- K_pack_w1: W1 f32 -> bf16 fragment-major ----------------
// w1t chunk c = (cg*32 + kt)*64 + l holds W1[col = cg*16 + (l&15)][k = kt*32 + (l>>4)*8 + j]
__global__ void k_pack_w1(const float* __restrict__ W1, unsigned short* __restrict__ w1t) {
  int c = blockIdx.x * 256 + threadIdx.x;   // [0, 131072)
  int l  = c & 63;
  int kt = (c >> 6) & 31;
  int cg = c >> 11;
  int col = cg * 16 + (l & 15);
  int k0  = kt * 32 + (l >> 4) * 8;
  const float* src = W1 + (size_t)col * D_ + k0;
  float4 x0 = *reinterpret_cast<const float4*>(src);
  float4 x1 = *reinterpret_cast<const float4*>(src + 4);
  uint4 w;
  w.x = f2b(x0.x) | ((unsigned)f2b(x0.y) << 16);
  w.y = f2b(x0.z) | ((unsigned)f2b(x0.w) << 16);
  w.z = f2b(x1.x) | ((unsigned)f2b(x1.y) << 16);
  w.w = f2b(x1.z) | ((unsigned)f2b(x1.w) << 16);
  reinterpret_cast<uint4*>(w1t)[c] = w;
}

// ---------------- K0: tdot[b] = h_t[b]·Wm_t + bmap ----------------
__global__ void k0_tdot(const float* __restrict__ h_t, const float* __restrict__ Wmap,
                        const float* __restrict__ bmap, float* __restrict__ tdot) {
  int b = blockIdx.x;
  int t = threadIdx.x;
  float p = 0.f;
  for (int k = t; k < D_; k += 256) p += h_t[b*D_ + k] * Wmap[D_ + k];
  __shared__ float red[256];
  red[t] = p; __syncthreads();
  for (int off = 128; off > 0; off >>= 1) { if (t < off) red[t] += red[t+off]; __syncthreads(); }
  if (t == 0) tdot[b] = red[0] + bmap[0];
}

// ---------------- K1 (fallback-only standalone gate) ----------------
__global__ void k1_gate(const float* __restrict__ aux, const float* __restrict__ Wmap,
                        const float* __restrict__ noise, const float* __restrict__ tdot,
                        float* __restrict__ Gout) {
  int w = (blockIdx.x * 256 + threadIdx.x) >> 6;
  int lane = threadIdx.x & 63;
  const float4* arow = reinterpret_cast<const float4*>(aux + (size_t)w * D_);
  const float4* wrow = reinterpret_cast<const float4*>(Wmap);
  float p = 0.f;
  for (int it = 0; it < 4; ++it) {
    float4 a = arow[it*64 + lane];
    float4 m = wrow[it*64 + lane];
    p += a.x*m.x + a.y*m.y + a.z*m.z + a.w*m.w;
  }
  for (int msk = 32; msk > 0; msk >>= 1) p += __shfl_xor(p, msk);
  if (lane == 0) {
    int b = w >> 11;
    float logits = p + tdot[b];
    float u = noise[w];
    u = fminf(fmaxf(u, 1e-7f), 1.f - 1e-7f);
    float logistic = logf(u) - log1pf(-u);
    float x = (logits + logistic) / TEMP_;
    Gout[w] = 1.f / (1.f + expf(-x));
  }
}

// ---------------- K2G: fused {gate role | GEMM role} single launch ----------------
// Blocks [0,1024): gate — G[row] = sigmoid((aux·Wm_a + tdot[b] + logistic(u))/T), 4 waves x 16 rows.
// Blocks [1024,3072): GEMM — r10's k2_breg verbatim (hw = bid-1024; 1024%8==0 keeps XCD swizzle).
// Rationale: GEMM uses <7% HBM; gate is a pure HBM stream with no dependency on GEMM inputs.
// 32 KiB dynamic LDS -> ~4 mixed blocks/CU co-resident; gate BW hides under GEMM compute.
extern __shared__ unsigned short lds2[];  // 4 bufs x 8 KiB = 32 KiB (GEMM role only)

__global__ __launch_bounds__(256, 2) void k2g(
    const unsigned short* __restrict__ Ag, const unsigned short* __restrict__ w1t,
    const float* __restrict__ b1, const float* __restrict__ W2,
    float* __restrict__ e_buf,
    const float* __restrict__ aux, const float* __restrict__ Wmap,
    const float* __restrict__ noise, const float* __restrict__ tdot,
    float* __restrict__ Gout) {
  int bid = blockIdx.x;
  int t = threadIdx.x;
  int lane = t & 63;
  int wv = t >> 6;

  if (bid < 1024) {
    // ---------------- gate role ----------------
    const float4* wrow = reinterpret_cast<const float4*>(Wmap);
    float4 m0 = wrow[lane], m1 = wrow[64 + lane], m2 = wrow[128 + lane], m3 = wrow[192 + lane];
    int gw = (bid << 2) | wv;                 // [0,4096)
#pragma unroll 2
    for (int i = 0; i < 16; ++i) {
      int row = (gw << 4) | i;                // [0,65536)
      const float4* arow = reinterpret_cast<const float4*>(aux + (size_t)row * D_);
      float4 a0 = arow[lane], a1 = arow[64 + lane], a2 = arow[128 + lane], a3 = arow[192 + lane];
      float p = a0.x*m0.x + a0.y*m0.y + a0.z*m0.z + a0.w*m0.w
              + a1.x*m1.x + a1.y*m1.y + a1.z*m1.z + a1.w*m1.w
              + a2.x*m2.x + a2.y*m2.y + a2.z*m2.z + a2.w*m2.w
              + a3.x*m3.x + a3.y*m3.y + a3.z*m3.z + a3.w*m3.w;
      for (int msk = 32; msk > 0; msk >>= 1) p += __shfl_xor(p, msk);
      if (lane == 0) {
        float logits = p + tdot[row >> 11];
        float u = noise[row];
        u = fminf(fmaxf(u, 1e-7f), 1.f - 1e-7f);
        float logistic = logf(u) - log1pf(-u);
        float x = (logits + logistic) / TEMP_;
        Gout[row] = 1.f / (1.f + expf(-x));
      }
    }
    return;
  }

  // ---------------- GEMM role (r10 k2_breg verbatim) ----------------
  int hw = bid - 1024;            // [0,2048)
  int xcd = hw & 7;
  int sub = hw >> 3;              // [0,256)
  int cc  = sub & 3;
  int rc  = xcd + 8 * (sub >> 2); // [0,512)
  int rowBase = rc * 128;
  int colBase = cc * 256;
  int kslot = lane >> 4;

  int aOff[8];
#pragma unroll
  for (int m = 0; m < 8; ++m) {
    int r = m * 16 + (lane & 15);
    aOff[m] = r * 64 + ((kslot ^ ((r >> 1) & 3)) << 4);
  }

  const unsigned short* gA[2];
  int dstA[2];
#pragma unroll
  for (int i = 0; i < 2; ++i) {
    int c = i * 256 + t;
    int r = c >> 2;
    int clog = (c & 3) ^ ((r >> 1) & 3);
    gA[i] = Ag + (size_t)(rowBase + r) * D_ + clog * 8;
    dstA[i] = c * 16;
  }

  const unsigned short* pB[4];
#pragma unroll
  for (int n = 0; n < 4; ++n) {
    int cg = (colBase >> 4) + wv * 4 + n;
    pB[n] = w1t + (size_t)cg * 16384 + lane * 8;
  }

  f32x4 acc[8][4] = {};
  short8 bfA[4], bfB[4];

#define STAGE(TT) do {                                                         \
    char* _ba = (char*)lds2 + ((TT) & 3) * 8192;                               \
    GLOAD_LDS16(gA[0] + (TT) * 32, _ba + dstA[0]);                             \
    GLOAD_LDS16(gA[1] + (TT) * 32, _ba + dstA[1]);                             \
  } while (0)

#define K2_TILE(T, VM, DO_B, DO_S, BFC, BFN) do {                              \
    asm volatile("s_waitcnt lgkmcnt(0)\n\ts_waitcnt vmcnt(" #VM ")" ::: "memory"); \
    __builtin_amdgcn_s_barrier();                                              \
    const char* _ab = (const char*)lds2 + ((T) & 3) * 8192;                    \
    short8 af[8];                                                              \
    _Pragma("unroll")                                                          \
    for (int m = 0; m < 8; ++m)                                                \
      af[m] = *reinterpret_cast<const short8*>(_ab + aOff[m]);                 \
    if (DO_B) {                                                                \
      _Pragma("unroll")                                                        \
      for (int n = 0; n < 4; ++n)                                              \
        BFN[n] = *reinterpret_cast<const short8*>(pB[n] + ((T) + 1) * 512);    \
    }                                                                          \
    if (DO_S) STAGE((T) + 3);                                                  \
    __builtin_amdgcn_s_setprio(1);                                             \
    _Pragma("unroll")                                                          \
    for (int m = 0; m < 8; ++m)                                                \
      _Pragma("unroll")                                                        \
      for (int n = 0; n < 4; ++n)                                              \
        acc[m][n] = __builtin_amdgcn_mfma_f32_16x16x32_bf16(af[m], BFC[n], acc[m][n], 0, 0, 0); \
    __builtin_amdgcn_s_setprio(0);                                             \
  } while (0)

  STAGE(0); STAGE(1); STAGE(2);
#pragma unroll
  for (int n = 0; n < 4; ++n)
    bfA[n] = *reinterpret_cast<const short8*>(pB[n]);

  K2_TILE(0, 0, true, true, bfA, bfB);
  K2_TILE(1, 2, true, true, bfB, bfA);
#pragma unroll
  for (int tt = 2; tt < 28; tt += 2) {
    K2_TILE(tt,     2, true, true, bfA, bfB);
    K2_TILE(tt + 1, 2, true, true, bfB, bfA);
  }
  K2_TILE(28, 2, true,  true,  bfA, bfB);   // stages tile 31
  K2_TILE(29, 2, true,  false, bfB, bfA);
  K2_TILE(30, 0, true,  false, bfA, bfB);
  K2_TILE(31, 0, false, false, bfB, bfA);
#undef K2_TILE
#undef STAGE

  float b1v[4], w2v[4];
#pragma unroll
  for (int n = 0; n < 4; ++n) {
    int col = colBase + wv * 64 + n * 16 + (lane & 15);
    b1v[n] = b1[col];
    w2v[n] = W2[col];
  }
#pragma unroll
  for (int m = 0; m < 8; ++m) {
#pragma unroll
    for (int j = 0; j < 4; ++j) {
      float s = 0.f;
#pragma unroll
      for (int n = 0; n < 4; ++n)
        s += tanh_fast(acc[m][n][j] + b1v[n]) * w2v[n];
      s += __shfl_xor(s, 1);
      s += __shfl_xor(s, 2);
      s += __shfl_xor(s, 4);
      s += __shfl_xor(s, 8);
      if ((lane & 15) == 0) {
        int row = rowBase + m * 16 + ((lane >> 4) << 2) + j;
        atomicAdd(&e_buf[row], s);
      }
    }
  }
}

// ---------------- K2 fallback (f32 inputs, reg-staged conversion, 128^2) ----------------
#define BM 128
#define BN 128
#define BK 64
__global__ __launch_bounds__(256) void k2_egemm_f32(
    const float* __restrict__ h_s, const float* __restrict__ W1,
    const float* __restrict__ b1, const float* __restrict__ W2,
    float* __restrict__ e_buf) {
  __shared__ unsigned short As[BM * BK];
  __shared__ unsigned short Bs[BN * BK];
  int bid = blockIdx.x;
  int colBase = (bid & 7) * BN;
  int rowBase = (bid >> 3) * BM;
  int t = threadIdx.x;
  int lane = t & 63;
  int wave = t >> 6;
  int wr = wave >> 1, wc = wave & 1;
  f32x4 acc[4][4] = {};
  for (int k0 = 0; k0 < D_; k0 += BK) {
    __syncthreads();
    for (int i = 0; i < 4; ++i) {
      int flat = i*256 + t;
      int r = flat >> 3;
      int c8 = flat & 7;
      int byte = (r*128 + c8*16) ^ ((r & 7) << 4);
      {
        const float4* g = reinterpret_cast<const float4*>(h_s + (size_t)(rowBase + r)*D_ + k0 + c8*8);
        float4 x0 = g[0], x1 = g[1];
        uint4 w;
        w.x = f2b(x0.x) | ((unsigned)f2b(x0.y) << 16);
        w.y = f2b(x0.z) | ((unsigned)f2b(x0.w) << 16);
        w.z = f2b(x1.x) | ((unsigned)f2b(x1.y) << 16);
        w.w = f2b(x1.z) | ((unsigned)f2b(x1.w) << 16);
        *reinterpret_cast<uint4*>(reinterpret_cast<char*>(As) + byte) = w;
      }
      {
        const float4* g = reinterpret_cast<const float4*>(W1 + (size_t)(colBase + r)*D_ + k0 + c8*8);
        float4 x0 = g[0], x1 = g[1];
        uint4 w;
        w.x = f2b(x0.x) | ((unsigned)f2b(x0.y) << 16);
        w.y = f2b(x0.z) | ((unsigned)f2b(x0.w) << 16);
        w.z = f2b(x1.x) | ((unsigned)f2b(x1.y) << 16);
        w.w = f2b(x1.z) | ((unsigned)f2b(x1.w) << 16);
        *reinterpret_cast<uint4*>(reinterpret_cast<char*>(Bs) + byte) = w;
      }
    }
    __syncthreads();
    for (int kk = 0; kk < BK; kk += 32) {
      short8 af[4], bf[4];
      int kByte = kk*2 + ((lane >> 4) << 4);
      for (int m = 0; m < 4; ++m) {
        int r = wr*64 + m*16 + (lane & 15);
        int byte = (r*128 + kByte) ^ ((r & 7) << 4);
        af[m] = *reinterpret_cast<const short8*>(reinterpret_cast<const char*>(As) + byte);
      }
      for (int n = 0; n < 4; ++n) {
        int r = wc*64 + n*16 + (lane & 15);
        int byte = (r*128 + kByte) ^ ((r & 7) << 4);
        bf[n] = *reinterpret_cast<const short8*>(reinterpret_cast<const char*>(Bs) + byte);
      }
      for (int m = 0; m < 4; ++m)
        for (int n = 0; n < 4; ++n)
          acc[m][n] = __builtin_amdgcn_mfma_f32_16x16x32_bf16(af[m], bf[n], acc[m][n], 0, 0, 0);
    }
  }
  float b1v[4], w2v[4];
  for (int n = 0; n < 4; ++n) {
    int col = colBase + wc*64 + n*16 + (lane & 15);
    b1v[n] = b1[col];
    w2v[n] = W2[col];
  }
  for (int m = 0; m < 4; ++m) {
    for (int j = 0; j < 4; ++j) {
      float s = 0.f;
      for (int n = 0; n < 4; ++n)
        s += tanhf(acc[m][n][j] + b1v[n]) * w2v[n];
      s += __shfl_xor(s, 1);
      s += __shfl_xor(s, 2);
      s += __shfl_xor(s, 4);
      s += __shfl_xor(s, 8);
      if ((lane & 15) == 0) {
        int row = rowBase + wr*64 + m*16 + ((lane >> 4) << 2) + j;
        atomicAdd(&e_buf[row], s);
      }
    }
  }
}

// ---------------- K3a: v[s] = max_b e[b,s] ----------------
__global__ void k3a_vmax(const float* __restrict__ e_buf, float* __restrict__ v) {
  int s = blockIdx.x * 256 + threadIdx.x;
  if (s >= S_) return;
  float m = -1e30f;
  for (int b = 0; b < B_; ++b) m = fmaxf(m, e_buf[b*S_ + s]);
  v[s] = m;
}

// ---------------- K3b: align = exp(e-v)*G / sum_s (in-place over G) ----------------
__global__ void k3b_align(const float* __restrict__ e_buf, const float* __restrict__ v,
                          float* __restrict__ galign) {
  int b = blockIdx.x;
  int t = threadIdx.x;
  __shared__ float sc[S_];
  __shared__ float red[256];
  float p = 0.f;
  for (int s = t; s < S_; s += 256) {
    float x = expf(e_buf[b*S_ + s] - v[s]) * galign[b*S_ + s];
    sc[s] = x;
    p += x;
  }
  red[t] = p; __syncthreads();
  for (int off = 128; off > 0; off >>= 1) { if (t < off) red[t] += red[t+off]; __syncthreads(); }
  float inv = 1.f / red[0];
  for (int s = t; s < S_; s += 256) galign[b*S_ + s] = sc[s] * inv;
}

// ---------------- K4 (bf16 h_s): c[b,:] = sum_s align[b,s]*h_s[b,s,:] ----------------
__global__ void k4_ctx_bf16(const unsigned short* __restrict__ hsb, const float* __restrict__ align,
                            float* __restrict__ c) {
  int bid = blockIdx.x;
  int b = bid >> 6;
  int sBase = (bid & 63) * 32;
  int t = threadIdx.x;
  float4 accv = {0.f, 0.f, 0.f, 0.f};
  for (int si = 0; si < 32; ++si) {
    int s = sBase + si;
    float a = align[b*S_ + s];
    ushort4v hv = *reinterpret_cast<const ushort4v*>(hsb + (size_t)(b*S_ + s)*D_ + t*4);
    accv.x += a*b2f(hv.x); accv.y += a*b2f(hv.y); accv.z += a*b2f(hv.z); accv.w += a*b2f(hv.w);
  }
  atomicAdd(&c[b*D_ + t*4 + 0], accv.x);
  atomicAdd(&c[b*D_ + t*4 + 1], accv.y);
  atomicAdd(&c[b*D_ + t*4 + 2], accv.z);
  atomicAdd(&c[b*D_ + t*4 + 3], accv.w);
}

// ---------------- K4 fallback (f32 h_s) ----------------
__global__ void k4_ctx_f32(const float* __restrict__ h_s, const float* __restrict__ align,
                           float* __restrict__ c) {
  int bid = blockIdx.x;
  int b = bid >> 6;
  int sBase = (bid & 63) * 32;
  int t = threadIdx.x;
  float4 accv = {0.f, 0.f, 0.f, 0.f};
  for (int si = 0; si < 32; ++si) {
    int s = sBase + si;
    float a = align[b*S_ + s];
    float4 hv = *reinterpret_cast<const float4*>(h_s + (size_t)(b*S_ + s)*D_ + t*4);
    accv.x += a*hv.x; accv.y += a*hv.y; accv.z += a*hv.z; accv.w += a*hv.w;
  }
  atomicAdd(&c[b*D_ + t*4 + 0], accv.x);
  atomicAdd(&c[b*D_ + t*4 + 1], accv.y);
  atomicAdd(&c[b*D_ + t*4 + 2], accv.z);
  atomicAdd(&c[b*D_ + t*4 + 3], accv.w);
}

// ---------------- K5: attn_h = tanh([c,h_t] @ Wout^T) ----------------
__global__ void k5_out(const float* __restrict__ c, const float* __restrict__ h_t,
                       const float* __restrict__ Wout, float* __restrict__ out) {
  int W = (blockIdx.x * 256 + threadIdx.x) >> 6;
  int lane = threadIdx.x & 63;
  int b = W >> 10;
  int o = W & 1023;
  const float* wrow = Wout + (size_t)o * (2 * D_);
  float p = 0.f;
  for (int it = 0; it < 16; ++it) {
    int k = it*64 + lane;
    p += c[b*D_ + k] * wrow[k];
  }
  for (int it = 16; it < 32; ++it) {
    int k = it*64 + lane;
    p += h_t[b*D_ + (k - D_)] * wrow[k];
  }
  for (int m = 32; m > 0; m >>= 1) p += __shfl_xor(p, m);
  if (lane == 0) out[b*D_ + o] = tanhf(p);
}

extern "C" void kernel_launch(void* const* d_in, const int* in_sizes, int n_in,
                              void* d_out, int out_size, void* d_ws, size_t ws_size,
                              hipStream_t stream) {
  const float* h_t   = (const float*)d_in[0];
  const float* h_s   = (const float*)d_in[1];
  const float* aux   = (const float*)d_in[2];
  const float* noise = (const float*)d_in[3];
  const float* Wmap  = (const float*)d_in[4];
  const float* bmap  = (const float*)d_in[5];
  const float* W1    = (const float*)d_in[6];
  const float* b1    = (const float*)d_in[7];
  const float* W2    = (const float*)d_in[8];
  // d_in[9] = b2: cancels exactly in exp(e-v)/sum -> unused
  const float* Wout  = (const float*)d_in[10];

  float* out    = (float*)d_out;          // [attn_h: 32768 | align: 65536]
  float* galign = out + B_*D_;            // holds G first, overwritten with align

  const size_t HS_N   = (size_t)B_*S_*D_;   // 64M
  const size_t W1_N   = (size_t)D_*D_;      // 1M
  const size_t needed = HS_N*2 + W1_N*2 + (65536 + 32 + 2048 + 32768) * sizeof(float);

  if (ws_size >= needed) {
    unsigned short* hs_bf = (unsigned short*)d_ws;                 // 128 MB
    unsigned short* w1t   = hs_bf + HS_N;                          // 2 MB (fragment-major)
    float* fws   = (float*)(w1t + W1_N);
    float* e_buf = fws;                     // 65536
    float* tdot  = fws + 65536;             // 32
    float* v     = fws + 65568;             // 2048
    float* c     = fws + 67616;             // 32768

    hipMemsetAsync(e_buf, 0, 65536 * sizeof(float), stream);
    hipMemsetAsync(c, 0, 32768 * sizeof(float), stream);

    hipFuncSetAttribute(reinterpret_cast<const void*>(k2g),
                        hipFuncAttributeMaxDynamicSharedMemorySize, 32768);

    k_conv<<<(int)(HS_N/8/256), 256, 0, stream>>>(h_s, hs_bf, (int)(HS_N/8));
    k_pack_w1<<<512, 256, 0, stream>>>(W1, w1t);
    k0_tdot<<<32, 256, 0, stream>>>(h_t, Wmap, bmap, tdot);
    k2g<<<3072, 256, 32768, stream>>>(hs_bf, w1t, b1, W2, e_buf,
                                      aux, Wmap, noise, tdot, galign);
    k3a_vmax<<<8, 256, 0, stream>>>(e_buf, v);
    k3b_align<<<32, 256, 0, stream>>>(e_buf, v, galign);
    k4_ctx_bf16<<<2048, 256, 0, stream>>>(hs_bf, galign, c);
    k5_out<<<8192, 256, 0, stream>>>(c, h_t, Wout, out);
  } else {
    float* ws    = (float*)d_ws;
    float* e_buf = ws;                      // 65536
    float* tdot  = ws + 65536;              // 32
    float* v     = ws + 65568;              // 2048
    float* c     = ws + 67616;              // 32768

    hipMemsetAsync(e_buf, 0, 65536 * sizeof(float), stream);
    hipMemsetAsync(c, 0, 32768 * sizeof(float), stream);

    k0_tdot<<<32, 256, 0, stream>>>(h_t, Wmap, bmap, tdot);
    k1_gate<<<16384, 256, 0, stream>>>(aux, Wmap, noise, tdot, galign);
    k2_egemm_f32<<<4096, 256, 0, stream>>>(h_s, W1, b1, W2, e_buf);
    k3a_vmax<<<8, 256, 0, stream>>>(e_buf, v);
    k3b_align<<<32, 256, 0, stream>>>(e_buf, v, galign);
    k4_ctx_f32<<<2048, 256, 0, stream>>>(h_s, galign, c);
    k5_out<<<8192, 256, 0, stream>>>(c, h_t, Wout, out);
  }
}

// Round 12
// 340.300 us; speedup vs baseline: 1.0453x; 1.0453x over previous
//
#include <hip/hip_runtime.h>
#include <hip/hip_bf16.h>
#include <math.h>

#define B_ 32
#define S_ 2048
#define D_ 1024
#define TEMP_ 9.0f

typedef __attribute__((ext_vector_type(8))) short short8;
typedef __attribute__((ext_vector_type(4))) float f32x4;
typedef __attribute__((ext_vector_type(4))) unsigned short ushort4v;

__device__ __forceinline__ unsigned short f2b(float f) {
  union { float f; unsigned int u; } v; v.f = f;
  unsigned int r = v.u;
  r += 0x7fffu + ((r >> 16) & 1u);   // RNE
  return (unsigned short)(r >> 16);
}
__device__ __forceinline__ float b2f(unsigned short b) {
  union { float f; unsigned int u; } v; v.u = ((unsigned int)b) << 16;
  return v.f;
}
// fast tanh: 1 - 2/(e^2x + 1); saturates correctly at +-inf
__device__ __forceinline__ float tanh_fast(float x) {
  float ez = __expf(2.f * x);
  return 1.f - __fdividef(2.f, ez + 1.f);
}

#define GLOAD_LDS16(g, l) \
  __builtin_amdgcn_global_load_lds((const __attribute__((address_space(1))) void*)(g), \
                                   (__attribute__((address_space(3))) void*)(l), 16, 0, 0)

// ---------------- K_conv: f32 -> bf16, 8 elements/thread ----------------
__global__ void k_conv(const float* __restrict__ src, unsigned short* __restrict__ dst, int n8) {
  int i = blockIdx.x * 256 + threadIdx.x;
  if (i >= n8) return;
  const float4* g = reinterpret_cast<const float4*>(src) + (size_t)i * 2;
  float4 x0 = g[0], x1 = g[1];
  uint4 w;
  w.x = f2b(x0.x) | ((unsigned)f2b(x0.y) << 16);
  w.y = f2b(x0.z) | ((unsigned)f2b(x0.w) << 16);
  w.z = f2b(x1.x) | ((unsigned)f2b(x1.y) << 16);
  w.w = f2b(x1.z) | ((unsigned)f2b(x1.w) << 16);
  reinterpret_cast<uint4*>(dst)[i] = w;
}

// ---------------- K_pack_w1: W1 f32 -> bf16 fragment-major ----------------
// w1t chunk c = (cg*32 + kt)*64 + l holds W1[col = cg*16 + (l&15)][k = kt*32 + (l>>4)*8 + j]
__global__ void k_pack_w1(const float* __restrict__ W1, unsigned short* __restrict__ w1t) {
  int c = blockIdx.x * 256 + threadIdx.x;   // [0, 131072)
  int l  = c & 63;
  int kt = (c >> 6) & 31;
  int cg = c >> 11;
  int col = cg * 16 + (l & 15);
  int k0  = kt * 32 + (l >> 4) * 8;
  const float* src = W1 + (size_t)col * D_ + k0;
  float4 x0 = *reinterpret_cast<const float4*>(src);
  float4 x1 = *reinterpret_cast<const float4*>(src + 4);
  uint4 w;
  w.x = f2b(x0.x) | ((unsigned)f2b(x0.y) << 16);
  w.y = f2b(x0.z) | ((unsigned)f2b(x0.w) << 16);
  w.z = f2b(x1.x) | ((unsigned)f2b(x1.y) << 16);
  w.w = f2b(x1.z) | ((unsigned)f2b(x1.w) << 16);
  reinterpret_cast<uint4*>(w1t)[c] = w;
}

// ---------------- K0: tdot[b] = h_t[b]·Wm_t + bmap ----------------
__global__ void k0_tdot(const float* __restrict__ h_t, const float* __restrict__ Wmap,
                        const float* __restrict__ bmap, float* __restrict__ tdot) {
  int b = blockIdx.x;
  int t = threadIdx.x;
  float p = 0.f;
  for (int k = t; k < D_; k += 256) p += h_t[b*D_ + k] * Wmap[D_ + k];
  __shared__ float red[256];
  red[t] = p; __syncthreads();
  for (int off = 128; off > 0; off >>= 1) { if (t < off) red[t] += red[t+off]; __syncthreads(); }
  if (t == 0) tdot[b] = red[0] + bmap[0];
}

// ---------------- K1 (fallback-only standalone gate) ----------------
__global__ void k1_gate(const float* __restrict__ aux, const float* __restrict__ Wmap,
                        const float* __restrict__ noise, const float* __restrict__ tdot,
                        float* __restrict__ Gout) {
  int w = (blockIdx.x * 256 + threadIdx.x) >> 6;
  int lane = threadIdx.x & 63;
  const float4* arow = reinterpret_cast<const float4*>(aux + (size_t)w * D_);
  const float4* wrow = reinterpret_cast<const float4*>(Wmap);
  float p = 0.f;
  for (int it = 0; it < 4; ++it) {
    float4 a = arow[it*64 + lane];
    float4 m = wrow[it*64 + lane];
    p += a.x*m.x + a.y*m.y + a.z*m.z + a.w*m.w;
  }
  for (int msk = 32; msk > 0; msk >>= 1) p += __shfl_xor(p, msk);
  if (lane == 0) {
    int b = w >> 11;
    float logits = p + tdot[b];
    float u = noise[w];
    u = fminf(fmaxf(u, 1e-7f), 1.f - 1e-7f);
    float logistic = logf(u) - log1pf(-u);
    float x = (logits + logistic) / TEMP_;
    Gout[w] = 1.f / (1.f + expf(-x));
  }
}

// ---------------- K2: r10's GEMM (verbatim) + per-block gate TAIL ----------------
// e[row] = sum_col tanh(h_s·W1[col,:] + b1[col]) * W2[col]
// Gate tail: each block computes 32 gate rows AFTER its epilogue. Blocks finish
// staggered, so gate HBM streams overlap other blocks' MFMA phases (GEMM uses <7% BW).
// No role-split blocks -> no dispatch-order sensitivity (r11's failure mode).
extern __shared__ unsigned short lds2[];  // 4 bufs x 8 KiB = 32 KiB

__global__ __launch_bounds__(256, 2) void k2gt(
    const unsigned short* __restrict__ Ag, const unsigned short* __restrict__ w1t,
    const float* __restrict__ b1, const float* __restrict__ W2,
    float* __restrict__ e_buf,
    const float* __restrict__ aux, const float* __restrict__ Wmap,
    const float* __restrict__ noise, const float* __restrict__ tdot,
    float* __restrict__ Gout) {
  // T1 bijective XCD swizzle: all 4 col-chunks of a row-chunk on one XCD, consecutive.
  int bid = blockIdx.x;           // [0,2048)
  int xcd = bid & 7;
  int sub = bid >> 3;             // [0,256)
  int cc  = sub & 3;
  int rc  = xcd + 8 * (sub >> 2); // [0,512)
  int rowBase = rc * 128;
  int colBase = cc * 256;

  int t = threadIdx.x;
  int lane = t & 63;
  int wv = t >> 6;                // 4 waves; wave output 128 rows x 64 cols
  int kslot = lane >> 4;

  // A ds-read byte offsets (within one 8 KiB buffer; swizzle verified 0-conflict r5/r8)
  int aOff[8];
#pragma unroll
  for (int m = 0; m < 8; ++m) {
    int r = m * 16 + (lane & 15);
    aOff[m] = r * 64 + ((kslot ^ ((r >> 1) & 3)) << 4);
  }

  // A stage sources (k0=0) + LDS dest offsets: 512 chunks of 16B, 2/thread
  const unsigned short* gA[2];
  int dstA[2];
#pragma unroll
  for (int i = 0; i < 2; ++i) {
    int c = i * 256 + t;
    int r = c >> 2;
    int clog = (c & 3) ^ ((r >> 1) & 3);
    gA[i] = Ag + (size_t)(rowBase + r) * D_ + clog * 8;
    dstA[i] = c * 16;
  }

  // B fragment base pointers: wave wv covers col-groups (colBase/16 + wv*4 + n)
  const unsigned short* pB[4];
#pragma unroll
  for (int n = 0; n < 4; ++n) {
    int cg = (colBase >> 4) + wv * 4 + n;
    pB[n] = w1t + (size_t)cg * 16384 + lane * 8;
  }

  f32x4 acc[8][4] = {};
  short8 bfA[4], bfB[4];

#define STAGE(TT) do {                                                         \
    char* _ba = (char*)lds2 + ((TT) & 3) * 8192;                               \
    GLOAD_LDS16(gA[0] + (TT) * 32, _ba + dstA[0]);                             \
    GLOAD_LDS16(gA[1] + (TT) * 32, _ba + dstA[1]);                             \
  } while (0)

  // Invariants (r10-verified):
  //  - lgkmcnt(0)+barrier at tile top: stage(T+3) into buf (T-1)&3 is WAR-safe.
  //  - vmcnt(VM): VM = vmem ops issued after B(T)'s loads = 2 (stage(T+2)) steady.
#define K2_TILE(T, VM, DO_B, DO_S, BFC, BFN) do {                              \
    asm volatile("s_waitcnt lgkmcnt(0)\n\ts_waitcnt vmcnt(" #VM ")" ::: "memory"); \
    __builtin_amdgcn_s_barrier();                                              \
    const char* _ab = (const char*)lds2 + ((T) & 3) * 8192;                    \
    short8 af[8];                                                              \
    _Pragma("unroll")                                                          \
    for (int m = 0; m < 8; ++m)                                                \
      af[m] = *reinterpret_cast<const short8*>(_ab + aOff[m]);                 \
    if (DO_B) {                                                                \
      _Pragma("unroll")                                                        \
      for (int n = 0; n < 4; ++n)                                              \
        BFN[n] = *reinterpret_cast<const short8*>(pB[n] + ((T) + 1) * 512);    \
    }                                                                          \
    if (DO_S) STAGE((T) + 3);                                                  \
    __builtin_amdgcn_s_setprio(1);                                             \
    _Pragma("unroll")                                                          \
    for (int m = 0; m < 8; ++m)                                                \
      _Pragma("unroll")                                                        \
      for (int n = 0; n < 4; ++n)                                              \
        acc[m][n] = __builtin_amdgcn_mfma_f32_16x16x32_bf16(af[m], BFC[n], acc[m][n], 0, 0, 0); \
    __builtin_amdgcn_s_setprio(0);                                             \
  } while (0)

  STAGE(0); STAGE(1); STAGE(2);
#pragma unroll
  for (int n = 0; n < 4; ++n)
    bfA[n] = *reinterpret_cast<const short8*>(pB[n]);

  K2_TILE(0, 0, true, true, bfA, bfB);
  K2_TILE(1, 2, true, true, bfB, bfA);
#pragma unroll
  for (int tt = 2; tt < 28; tt += 2) {
    K2_TILE(tt,     2, true, true, bfA, bfB);
    K2_TILE(tt + 1, 2, true, true, bfB, bfA);
  }
  K2_TILE(28, 2, true,  true,  bfA, bfB);   // stages tile 31
  K2_TILE(29, 2, true,  false, bfB, bfA);
  K2_TILE(30, 0, true,  false, bfA, bfB);
  K2_TILE(31, 0, false, false, bfB, bfA);
#undef K2_TILE
#undef STAGE

  // epilogue: e-partial = sum over this block's 256 cols of tanh(pre+b1)*W2
  float b1v[4], w2v[4];
#pragma unroll
  for (int n = 0; n < 4; ++n) {
    int col = colBase + wv * 64 + n * 16 + (lane & 15);
    b1v[n] = b1[col];
    w2v[n] = W2[col];
  }
#pragma unroll
  for (int m = 0; m < 8; ++m) {
#pragma unroll
    for (int j = 0; j < 4; ++j) {
      float s = 0.f;
#pragma unroll
      for (int n = 0; n < 4; ++n)
        s += tanh_fast(acc[m][n][j] + b1v[n]) * w2v[n];
      s += __shfl_xor(s, 1);
      s += __shfl_xor(s, 2);
      s += __shfl_xor(s, 4);
      s += __shfl_xor(s, 8);
      if ((lane & 15) == 0) {
        int row = rowBase + m * 16 + ((lane >> 4) << 2) + j;
        atomicAdd(&e_buf[row], s);
      }
    }
  }

  // ---- gate tail: 32 rows per block (8 per wave); overlaps other blocks' main loops ----
  {
    const float4* wrow = reinterpret_cast<const float4*>(Wmap);
    float4 m0 = wrow[lane], m1 = wrow[64 + lane], m2 = wrow[128 + lane], m3 = wrow[192 + lane];
    int rowG = (bid << 5) | (wv << 3);         // [0,65536), 8 rows for this wave
#pragma unroll 2
    for (int i = 0; i < 8; ++i) {
      int row = rowG + i;
      const float4* arow = reinterpret_cast<const float4*>(aux + (size_t)row * D_);
      float4 a0 = arow[lane], a1 = arow[64 + lane], a2 = arow[128 + lane], a3 = arow[192 + lane];
      float p = a0.x*m0.x + a0.y*m0.y + a0.z*m0.z + a0.w*m0.w
              + a1.x*m1.x + a1.y*m1.y + a1.z*m1.z + a1.w*m1.w
              + a2.x*m2.x + a2.y*m2.y + a2.z*m2.z + a2.w*m2.w
              + a3.x*m3.x + a3.y*m3.y + a3.z*m3.z + a3.w*m3.w;
      for (int msk = 32; msk > 0; msk >>= 1) p += __shfl_xor(p, msk);
      if (lane == 0) {
        float logits = p + tdot[row >> 11];
        float u = noise[row];
        u = fminf(fmaxf(u, 1e-7f), 1.f - 1e-7f);
        float logistic = logf(u) - log1pf(-u);
        float x = (logits + logistic) / TEMP_;
        Gout[row] = 1.f / (1.f + expf(-x));
      }
    }
  }
}

// ---------------- K2 fallback (f32 inputs, reg-staged conversion, 128^2) ----------------
#define BM 128
#define BN 128
#define BK 64
__global__ __launch_bounds__(256) void k2_egemm_f32(
    const float* __restrict__ h_s, const float* __restrict__ W1,
    const float* __restrict__ b1, const float* __restrict__ W2,
    float* __restrict__ e_buf) {
  __shared__ unsigned short As[BM * BK];
  __shared__ unsigned short Bs[BN * BK];
  int bid = blockIdx.x;
  int colBase = (bid & 7) * BN;
  int rowBase = (bid >> 3) * BM;
  int t = threadIdx.x;
  int lane = t & 63;
  int wave = t >> 6;
  int wr = wave >> 1, wc = wave & 1;
  f32x4 acc[4][4] = {};
  for (int k0 = 0; k0 < D_; k0 += BK) {
    __syncthreads();
    for (int i = 0; i < 4; ++i) {
      int flat = i*256 + t;
      int r = flat >> 3;
      int c8 = flat & 7;
      int byte = (r*128 + c8*16) ^ ((r & 7) << 4);
      {
        const float4* g = reinterpret_cast<const float4*>(h_s + (size_t)(rowBase + r)*D_ + k0 + c8*8);
        float4 x0 = g[0], x1 = g[1];
        uint4 w;
        w.x = f2b(x0.x) | ((unsigned)f2b(x0.y) << 16);
        w.y = f2b(x0.z) | ((unsigned)f2b(x0.w) << 16);
        w.z = f2b(x1.x) | ((unsigned)f2b(x1.y) << 16);
        w.w = f2b(x1.z) | ((unsigned)f2b(x1.w) << 16);
        *reinterpret_cast<uint4*>(reinterpret_cast<char*>(As) + byte) = w;
      }
      {
        const float4* g = reinterpret_cast<const float4*>(W1 + (size_t)(colBase + r)*D_ + k0 + c8*8);
        float4 x0 = g[0], x1 = g[1];
        uint4 w;
        w.x = f2b(x0.x) | ((unsigned)f2b(x0.y) << 16);
        w.y = f2b(x0.z) | ((unsigned)f2b(x0.w) << 16);
        w.z = f2b(x1.x) | ((unsigned)f2b(x1.y) << 16);
        w.w = f2b(x1.z) | ((unsigned)f2b(x1.w) << 16);
        *reinterpret_cast<uint4*>(reinterpret_cast<char*>(Bs) + byte) = w;
      }
    }
    __syncthreads();
    for (int kk = 0; kk < BK; kk += 32) {
      short8 af[4], bf[4];
      int kByte = kk*2 + ((lane >> 4) << 4);
      for (int m = 0; m < 4; ++m) {
        int r = wr*64 + m*16 + (lane & 15);
        int byte = (r*128 + kByte) ^ ((r & 7) << 4);
        af[m] = *reinterpret_cast<const short8*>(reinterpret_cast<const char*>(As) + byte);
      }
      for (int n = 0; n < 4; ++n) {
        int r = wc*64 + n*16 + (lane & 15);
        int byte = (r*128 + kByte) ^ ((r & 7) << 4);
        bf[n] = *reinterpret_cast<const short8*>(reinterpret_cast<const char*>(Bs) + byte);
      }
      for (int m = 0; m < 4; ++m)
        for (int n = 0; n < 4; ++n)
          acc[m][n] = __builtin_amdgcn_mfma_f32_16x16x32_bf16(af[m], bf[n], acc[m][n], 0, 0, 0);
    }
  }
  float b1v[4], w2v[4];
  for (int n = 0; n < 4; ++n) {
    int col = colBase + wc*64 + n*16 + (lane & 15);
    b1v[n] = b1[col];
    w2v[n] = W2[col];
  }
  for (int m = 0; m < 4; ++m) {
    for (int j = 0; j < 4; ++j) {
      float s = 0.f;
      for (int n = 0; n < 4; ++n)
        s += tanhf(acc[m][n][j] + b1v[n]) * w2v[n];
      s += __shfl_xor(s, 1);
      s += __shfl_xor(s, 2);
      s += __shfl_xor(s, 4);
      s += __shfl_xor(s, 8);
      if ((lane & 15) == 0) {
        int row = rowBase + wr*64 + m*16 + ((lane >> 4) << 2) + j;
        atomicAdd(&e_buf[row], s);
      }
    }
  }
}

// ---------------- K3a: v[s] = max_b e[b,s] ----------------
__global__ void k3a_vmax(const float* __restrict__ e_buf, float* __restrict__ v) {
  int s = blockIdx.x * 256 + threadIdx.x;
  if (s >= S_) return;
  float m = -1e30f;
  for (int b = 0; b < B_; ++b) m = fmaxf(m, e_buf[b*S_ + s]);
  v[s] = m;
}

// ---------------- K3b: align = exp(e-v)*G / sum_s (in-place over G) ----------------
__global__ void k3b_align(const float* __restrict__ e_buf, const float* __restrict__ v,
                          float* __restrict__ galign) {
  int b = blockIdx.x;
  int t = threadIdx.x;
  __shared__ float sc[S_];
  __shared__ float red[256];
  float p = 0.f;
  for (int s = t; s < S_; s += 256) {
    float x = expf(e_buf[b*S_ + s] - v[s]) * galign[b*S_ + s];
    sc[s] = x;
    p += x;
  }
  red[t] = p; __syncthreads();
  for (int off = 128; off > 0; off >>= 1) { if (t < off) red[t] += red[t+off]; __syncthreads(); }
  float inv = 1.f / red[0];
  for (int s = t; s < S_; s += 256) galign[b*S_ + s] = sc[s] * inv;
}

// ---------------- K4 (bf16 h_s): c[b,:] = sum_s align[b,s]*h_s[b,s,:] ----------------
__global__ void k4_ctx_bf16(const unsigned short* __restrict__ hsb, const float* __restrict__ align,
                            float* __restrict__ c) {
  int bid = blockIdx.x;
  int b = bid >> 6;
  int sBase = (bid & 63) * 32;
  int t = threadIdx.x;
  float4 accv = {0.f, 0.f, 0.f, 0.f};
  for (int si = 0; si < 32; ++si) {
    int s = sBase + si;
    float a = align[b*S_ + s];
    ushort4v hv = *reinterpret_cast<const ushort4v*>(hsb + (size_t)(b*S_ + s)*D_ + t*4);
    accv.x += a*b2f(hv.x); accv.y += a*b2f(hv.y); accv.z += a*b2f(hv.z); accv.w += a*b2f(hv.w);
  }
  atomicAdd(&c[b*D_ + t*4 + 0], accv.x);
  atomicAdd(&c[b*D_ + t*4 + 1], accv.y);
  atomicAdd(&c[b*D_ + t*4 + 2], accv.z);
  atomicAdd(&c[b*D_ + t*4 + 3], accv.w);
}

// ---------------- K4 fallback (f32 h_s) ----------------
__global__ void k4_ctx_f32(const float* __restrict__ h_s, const float* __restrict__ align,
                           float* __restrict__ c) {
  int bid = blockIdx.x;
  int b = bid >> 6;
  int sBase = (bid & 63) * 32;
  int t = threadIdx.x;
  float4 accv = {0.f, 0.f, 0.f, 0.f};
  for (int si = 0; si < 32; ++si) {
    int s = sBase + si;
    float a = align[b*S_ + s];
    float4 hv = *reinterpret_cast<const float4*>(h_s + (size_t)(b*S_ + s)*D_ + t*4);
    accv.x += a*hv.x; accv.y += a*hv.y; accv.z += a*hv.z; accv.w += a*hv.w;
  }
  atomicAdd(&c[b*D_ + t*4 + 0], accv.x);
  atomicAdd(&c[b*D_ + t*4 + 1], accv.y);
  atomicAdd(&c[b*D_ + t*4 + 2], accv.z);
  atomicAdd(&c[b*D_ + t*4 + 3], accv.w);
}

// ---------------- K5: attn_h = tanh([c,h_t] @ Wout^T) ----------------
__global__ void k5_out(const float* __restrict__ c, const float* __restrict__ h_t,
                       const float* __restrict__ Wout, float* __restrict__ out) {
  int W = (blockIdx.x * 256 + threadIdx.x) >> 6;
  int lane = threadIdx.x & 63;
  int b = W >> 10;
  int o = W & 1023;
  const float* wrow = Wout + (size_t)o * (2 * D_);
  float p = 0.f;
  for (int it = 0; it < 16; ++it) {
    int k = it*64 + lane;
    p += c[b*D_ + k] * wrow[k];
  }
  for (int it = 16; it < 32; ++it) {
    int k = it*64 + lane;
    p += h_t[b*D_ + (k - D_)] * wrow[k];
  }
  for (int m = 32; m > 0; m >>= 1) p += __shfl_xor(p, m);
  if (lane == 0) out[b*D_ + o] = tanhf(p);
}

extern "C" void kernel_launch(void* const* d_in, const int* in_sizes, int n_in,
                              void* d_out, int out_size, void* d_ws, size_t ws_size,
                              hipStream_t stream) {
  const float* h_t   = (const float*)d_in[0];
  const float* h_s   = (const float*)d_in[1];
  const float* aux   = (const float*)d_in[2];
  const float* noise = (const float*)d_in[3];
  const float* Wmap  = (const float*)d_in[4];
  const float* bmap  = (const float*)d_in[5];
  const float* W1    = (const float*)d_in[6];
  const float* b1    = (const float*)d_in[7];
  const float* W2    = (const float*)d_in[8];
  // d_in[9] = b2: cancels exactly in exp(e-v)/sum -> unused
  const float* Wout  = (const float*)d_in[10];

  float* out    = (float*)d_out;          // [attn_h: 32768 | align: 65536]
  float* galign = out + B_*D_;            // holds G first, overwritten with align

  const size_t HS_N   = (size_t)B_*S_*D_;   // 64M
  const size_t W1_N   = (size_t)D_*D_;      // 1M
  const size_t needed = HS_N*2 + W1_N*2 + (65536 + 32 + 2048 + 32768) * sizeof(float);

  if (ws_size >= needed) {
    unsigned short* hs_bf = (unsigned short*)d_ws;                 // 128 MB
    unsigned short* w1t   = hs_bf + HS_N;                          // 2 MB (fragment-major)
    float* fws   = (float*)(w1t + W1_N);
    float* e_buf = fws;                     // 65536
    float* tdot  = fws + 65536;             // 32
    float* v     = fws + 65568;             // 2048
    float* c     = fws + 67616;             // 32768

    hipMemsetAsync(e_buf, 0, 65536 * sizeof(float), stream);
    hipMemsetAsync(c, 0, 32768 * sizeof(float), stream);

    hipFuncSetAttribute(reinterpret_cast<const void*>(k2gt),
                        hipFuncAttributeMaxDynamicSharedMemorySize, 32768);

    k_conv<<<(int)(HS_N/8/256), 256, 0, stream>>>(h_s, hs_bf, (int)(HS_N/8));
    k_pack_w1<<<512, 256, 0, stream>>>(W1, w1t);
    k0_tdot<<<32, 256, 0, stream>>>(h_t, Wmap, bmap, tdot);
    k2gt<<<2048, 256, 32768, stream>>>(hs_bf, w1t, b1, W2, e_buf,
                                       aux, Wmap, noise, tdot, galign);
    k3a_vmax<<<8, 256, 0, stream>>>(e_buf, v);
    k3b_align<<<32, 256, 0, stream>>>(e_buf, v, galign);
    k4_ctx_bf16<<<2048, 256, 0, stream>>>(hs_bf, galign, c);
    k5_out<<<8192, 256, 0, stream>>>(c, h_t, Wout, out);
  } else {
    float* ws    = (float*)d_ws;
    float* e_buf = ws;                      // 65536
    float* tdot  = ws + 65536;              // 32
    float* v     = ws + 65568;              // 2048
    float* c     = ws + 67616;              // 32768

    hipMemsetAsync(e_buf, 0, 65536 * sizeof(float), stream);
    hipMemsetAsync(c, 0, 32768 * sizeof(float), stream);

    k0_tdot<<<32, 256, 0, stream>>>(h_t, Wmap, bmap, tdot);
    k1_gate<<<16384, 256, 0, stream>>>(aux, Wmap, noise, tdot, galign);
    k2_egemm_f32<<<4096, 256, 0, stream>>>(h_s, W1, b1, W2, e_buf);
    k3a_vmax<<<8, 256, 0, stream>>>(e_buf, v);
    k3b_align<<<32, 256, 0, stream>>>(e_buf, v, galign);
    k4_ctx_f32<<<2048, 256, 0, stream>>>(h_s, galign, c);
    k5_out<<<8192, 256, 0, stream>>>(c, h_t, Wout, out);
  }
}